// Round 3
// baseline (332.021 us; speedup 1.0000x reference)
//
#include <hip/hip_runtime.h>

// GraphFilter B=16,T=64,F=64,N=128,E=2,K=4 — fully fused bf16 MFMA chain.
// Per output block (b,t), per e:
//   A = U3[t-3]
//   A = A@S[t-2] + U2[t-2]
//   A = A@S[t-1] + U1[t-1]
//   accY += A@S[t] + U0[t]
// with U_k[s][o][n] = sum_f H[o,e,k,f] x[s,f,n], boundary terms dropped.
// Same FLOPs as the 3-pass Horner pipeline but zero intermediate global traffic.
// MFMA 16x16x32 bf16: A[m=lane&15][k=quad*8+j], B[n=lane&15][k=quad*8+j],
// C/D col=lane&15, row=quad*4+reg.  S pre-transposed to bf16 [n][m] (cvt_S);
// H pre-converted to bf16 [e][k][o][f] (cvt_H).

namespace {
constexpr int B = 16, T = 64, F = 64, N = 128, E = 2, K = 4;
constexpr int SH = 72;   // sH stride  [64][72]
constexpr int SX = 72;   // sB stride  [128][72] (x^T tile or S^T half tile)
constexpr int SA = 136;  // sA stride  [64][136] (A-operand round-trip)
}

typedef short v8s __attribute__((ext_vector_type(8)));
typedef float v4f __attribute__((ext_vector_type(4)));

__device__ inline ushort f2bf(float f) {
  union { float f; uint u; } v; v.f = f;
  uint u = v.u;
  return (ushort)((u + 0x7fffu + ((u >> 16) & 1u)) >> 16);
}

__device__ inline uint4 pack8(const ushort* p) {
  uint4 w;
  w.x = (uint)p[0] | ((uint)p[1] << 16);
  w.y = (uint)p[2] | ((uint)p[3] << 16);
  w.z = (uint)p[4] | ((uint)p[5] << 16);
  w.w = (uint)p[6] | ((uint)p[7] << 16);
  return w;
}

// ---- H: fp32 [o][e][k][f] -> bf16 [e][k][o][f] ----
__global__ __launch_bounds__(256) void cvt_H(const float* __restrict__ H,
                                             ushort* __restrict__ Hb) {
  const int d4 = blockIdx.x * 256 + threadIdx.x;   // 8192 threads x 4 elems
  const int d = d4 * 4;
  const int f = d & 63, o = (d >> 6) & 63, k = (d >> 12) & 3, e = (d >> 14) & 1;
  const float4 v = *(const float4*)(H + (((size_t)o * E + e) * K + k) * F + f);
  uint2 w;
  w.x = (uint)f2bf(v.x) | ((uint)f2bf(v.y) << 16);
  w.y = (uint)f2bf(v.z) | ((uint)f2bf(v.w) << 16);
  *(uint2*)(Hb + d) = w;
}

// ---- S: fp32 [m][n] -> bf16 [n][m] ----
__global__ __launch_bounds__(256) void cvt_S(const float* __restrict__ S,
                                             ushort* __restrict__ ST) {
  __shared__ ushort tile[128 * 130];
  const int bid = blockIdx.x;              // (b*T+s)*E+e
  const float* Sg = S + (size_t)bid * N * N;
  ushort* Og = ST + (size_t)bid * N * N;
  const int tid = threadIdx.x;
  #pragma unroll
  for (int it = 0; it < 16; ++it) {
    const int idx = tid + it * 256;
    const int m = idx >> 5, n4 = (idx & 31) * 4;
    const float4 v = *(const float4*)(Sg + m * N + n4);
    uint* lp = (uint*)&tile[m * 130 + n4];
    lp[0] = (uint)f2bf(v.x) | ((uint)f2bf(v.y) << 16);
    lp[1] = (uint)f2bf(v.z) | ((uint)f2bf(v.w) << 16);
  }
  __syncthreads();
  #pragma unroll
  for (int it = 0; it < 4; ++it) {
    const int idx = tid + it * 256;          // 0..1023
    const int m8 = (idx & 15) * 8, n2 = idx >> 4;
    uint r[8];
    #pragma unroll
    for (int j = 0; j < 8; ++j)
      r[j] = *(const uint*)&tile[(m8 + j) * 130 + 2 * n2];
    uint4 w0, w1;
    w0.x = (r[0] & 0xffffu) | (r[1] << 16);
    w0.y = (r[2] & 0xffffu) | (r[3] << 16);
    w0.z = (r[4] & 0xffffu) | (r[5] << 16);
    w0.w = (r[6] & 0xffffu) | (r[7] << 16);
    w1.x = (r[0] >> 16) | (r[1] & 0xffff0000u);
    w1.y = (r[2] >> 16) | (r[3] & 0xffff0000u);
    w1.z = (r[4] >> 16) | (r[5] & 0xffff0000u);
    w1.w = (r[6] >> 16) | (r[7] & 0xffff0000u);
    *(uint4*)(Og + (2 * n2) * N + m8) = w0;
    *(uint4*)(Og + (2 * n2 + 1) * N + m8) = w1;
  }
}

// ---- staging ----
__device__ inline void stage_Hb(const ushort* __restrict__ Hb, int e, int k,
                                ushort* sH, int tid) {
  const ushort* src = Hb + (size_t)((e * K + k) * 64) * 64;
  #pragma unroll
  for (int it = 0; it < 2; ++it) {
    const int idx = tid + it * 256;          // 0..511
    const int o = idx >> 3, f8 = (idx & 7) * 8;
    *(uint4*)&sH[o * SH + f8] = *(const uint4*)(src + o * 64 + f8);
  }
}

// x[b,s] fp32 [f][n] -> sB bf16 [n][f]
__device__ inline void stage_X(const float* __restrict__ xg, ushort* sB, int tid) {
  #pragma unroll
  for (int it = 0; it < 4; ++it) {
    const int idx = tid + it * 256;          // 0..1023
    const int n = idx & 127, f8 = (idx >> 7) * 8;
    ushort p[8];
    #pragma unroll
    for (int j = 0; j < 8; ++j) p[j] = f2bf(xg[(f8 + j) * N + n]);
    *(uint4*)&sB[n * SX + f8] = pack8(p);
  }
}

// S^T half h: [n][h*64 + 0..63]
__device__ inline void stage_Sh(const ushort* __restrict__ STg, int h,
                                ushort* sB, int tid) {
  #pragma unroll
  for (int it = 0; it < 4; ++it) {
    const int idx = tid + it * 256;          // 0..1023
    const int n = idx >> 3, m8 = (idx & 7) * 8;
    *(uint4*)&sB[n * SX + m8] = *(const uint4*)(STg + n * N + h * 64 + m8);
  }
}

// ---- MFMA tiles (per wave: 32 o x 64 n) ----
__device__ inline void zero_acc(v4f acc[2][4]) {
  #pragma unroll
  for (int i = 0; i < 2; ++i)
    #pragma unroll
    for (int j = 0; j < 4; ++j) {
      acc[i][j][0] = 0.f; acc[i][j][1] = 0.f; acc[i][j][2] = 0.f; acc[i][j][3] = 0.f;
    }
}

__device__ inline void do_proj(const ushort* sH, const ushort* sB, v4f acc[2][4],
                               int ob0, int nb0, int l15, int q) {
  #pragma unroll
  for (int fk = 0; fk < 2; ++fk) {
    v8s a[2], bb[4];
    #pragma unroll
    for (int mt = 0; mt < 2; ++mt)
      a[mt] = *(const v8s*)&sH[(ob0 + 16 * mt + l15) * SH + fk * 32 + q * 8];
    #pragma unroll
    for (int nt = 0; nt < 4; ++nt)
      bb[nt] = *(const v8s*)&sB[(nb0 + 16 * nt + l15) * SX + fk * 32 + q * 8];
    #pragma unroll
    for (int mt = 0; mt < 2; ++mt)
      #pragma unroll
      for (int nt = 0; nt < 4; ++nt)
        acc[mt][nt] = __builtin_amdgcn_mfma_f32_16x16x32_bf16(
            a[mt], bb[nt], acc[mt][nt], 0, 0, 0);
  }
}

__device__ inline void do_mm(const ushort* sA, const ushort* sB, int h,
                             v4f acc[2][4], int ob0, int nb0, int l15, int q) {
  #pragma unroll
  for (int lk = 0; lk < 2; ++lk) {
    v8s a[2], bb[4];
    #pragma unroll
    for (int mt = 0; mt < 2; ++mt)
      a[mt] = *(const v8s*)&sA[(ob0 + 16 * mt + l15) * SA + h * 64 + lk * 32 + q * 8];
    #pragma unroll
    for (int nt = 0; nt < 4; ++nt)
      bb[nt] = *(const v8s*)&sB[(nb0 + 16 * nt + l15) * SX + lk * 32 + q * 8];
    #pragma unroll
    for (int mt = 0; mt < 2; ++mt)
      #pragma unroll
      for (int nt = 0; nt < 4; ++nt)
        acc[mt][nt] = __builtin_amdgcn_mfma_f32_16x16x32_bf16(
            a[mt], bb[nt], acc[mt][nt], 0, 0, 0);
  }
}

__device__ inline void store_sA(ushort* sA, v4f acc[2][4],
                                int ob0, int nb0, int l15, int q) {
  #pragma unroll
  for (int mt = 0; mt < 2; ++mt)
    #pragma unroll
    for (int nt = 0; nt < 4; ++nt) {
      const int col = nb0 + 16 * nt + l15;
      #pragma unroll
      for (int r = 0; r < 4; ++r)
        sA[(ob0 + 16 * mt + q * 4 + r) * SA + col] = f2bf(acc[mt][nt][r]);
    }
}

// ---- fused chain kernel: one block per (b,t) ----
__global__ __launch_bounds__(256, 3) void gf_fused(
    const float* __restrict__ x, const ushort* __restrict__ ST,
    const ushort* __restrict__ Hb, const float* __restrict__ bias,
    float* __restrict__ y) {
  __shared__ ushort sH[64 * SH];    //  9.2 KB
  __shared__ ushort sB[128 * SX];   // 18.4 KB
  __shared__ ushort sA[64 * SA];    // 17.4 KB  -> 45 KB total, 3 blocks/CU
  const int bid = blockIdx.x;
  const int t = bid % T, b = bid / T;
  const int tid = threadIdx.x, w = tid >> 6, lane = tid & 63;
  const int l15 = lane & 15, q = lane >> 4;
  const int ob0 = (w & 1) * 32, nb0 = (w >> 1) * 64;

  v4f accY[2][4];
  v4f acc[2][4];
  zero_acc(accY);

  for (int e = 0; e < E; ++e) {
    bool have = false;  // acc holds a live W_{k+1}[s-1]
    zero_acc(acc);
    #pragma unroll
    for (int k = 3; k >= 0; --k) {
      const int s = t - k;
      if (s < 0) continue;
      const bool prevP = have;
      __syncthreads();                    // prior readers of sA/sH/sB done
      if (prevP) store_sA(sA, acc, ob0, nb0, l15, q);
      stage_Hb(Hb, e, k, sH, tid);
      stage_X(x + (size_t)(b * T + s) * F * N, sB, tid);
      __syncthreads();
      if (k == 0) {
        do_proj(sH, sB, accY, ob0, nb0, l15, q);
      } else {
        zero_acc(acc);
        do_proj(sH, sB, acc, ob0, nb0, l15, q);
      }
      if (prevP) {
        const ushort* STg = ST + (size_t)((b * T + s) * E + e) * N * N;
        #pragma unroll
        for (int h = 0; h < 2; ++h) {
          __syncthreads();
          stage_Sh(STg, h, sB, tid);
          __syncthreads();
          if (k == 0) do_mm(sA, sB, h, accY, ob0, nb0, l15, q);
          else        do_mm(sA, sB, h, acc,  ob0, nb0, l15, q);
        }
      }
      have = true;
    }
  }

  float* yg = y + (size_t)(b * T + t) * F * N;
  #pragma unroll
  for (int mt = 0; mt < 2; ++mt)
    #pragma unroll
    for (int nt = 0; nt < 4; ++nt) {
      const int col = nb0 + 16 * nt + l15;
      #pragma unroll
      for (int r = 0; r < 4; ++r) {
        const int row = ob0 + 16 * mt + q * 4 + r;
        yg[row * N + col] = accY[mt][nt][r] + bias[row];
      }
    }
}

extern "C" void kernel_launch(void* const* d_in, const int* in_sizes, int n_in,
                              void* d_out, int out_size, void* d_ws, size_t ws_size,
                              hipStream_t stream) {
  const float* x    = (const float*)d_in[0];
  const float* S    = (const float*)d_in[1];
  const float* H    = (const float*)d_in[2];
  const float* bias = (const float*)d_in[3];
  float* y = (float*)d_out;

  const size_t STn = (size_t)B * T * E * N * N;   // 33,554,432 ushorts (64 MB)
  ushort* ST = (ushort*)d_ws;
  ushort* Hb = ST + STn;                          // 32768 ushorts

  cvt_H   <<<32,        256, 0, stream>>>(H, Hb);
  cvt_S   <<<B * T * E, 256, 0, stream>>>(S, ST);
  gf_fused<<<B * T,     256, 0, stream>>>(x, ST, Hb, bias, y);
}